// Round 1
// baseline (101.076 us; speedup 1.0000x reference)
//
#include <hip/hip_runtime.h>

// Problem constants (fixed by reference setup_inputs)
#define HW 262144    // 512*512 pixels per image
#define NB 8         // batch
#define NC 32        // channels
#define NK 8         // num classes (NUM_IDS)

// ws layout (floats):
//   sums   [8][8][32] at    0  (2048)   per-image per-class channel sums
//   counts [8][8]     at 2048  (64)
//   meansT [8][32][8] at 2112  (2048)   transposed: [b][c][k]
//   distsum[8][8]     at 4160  (64)
#define WS_SUMS 0
#define WS_CNT  2048
#define WS_MT   2112
#define WS_DS   4160
#define WS_FLOATS 4224

// ---------------------------------------------------------------------------
// Pass 1: per-class channel sums. One block = (image b, channel c, 16K-pixel
// chunk). Per-thread private LDS slots (stride 9 to de-pow2 banks), single
// flush per block. blockIdx layout: b = f&7 so XCD (heuristic f%8) owns one
// image -> label re-reads across the 32 channel-blocks of a chunk hit L2.
// ---------------------------------------------------------------------------
__global__ __launch_bounds__(256) void k_sums(const float* __restrict__ emb,
                                              const int* __restrict__ lab,
                                              float* __restrict__ sums) {
    __shared__ float slots[256 * 9];
    __shared__ float red[256];
    const int t = threadIdx.x;
    const int f = blockIdx.x;
    const int b = f & 7;
    const int o = f >> 3;        // 0..511 per image
    const int chunk = o >> 5;    // 0..15
    const int c = o & 31;

    float* myslot = &slots[t * 9];
#pragma unroll
    for (int i = 0; i < 9; ++i) myslot[i] = 0.f;

    const float* e = emb + ((size_t)(b * NC + c)) * HW;
    const int* lb = lab + (size_t)b * HW;
    const int base = chunk * 16384;

    for (int it = 0; it < 16; ++it) {
        const int p = base + it * 1024 + t * 4;
        const int4 l4 = *reinterpret_cast<const int4*>(lb + p);
        const float4 e4 = *reinterpret_cast<const float4*>(e + p);
        myslot[l4.x] += e4.x;
        myslot[l4.y] += e4.y;
        myslot[l4.z] += e4.z;
        myslot[l4.w] += e4.w;
    }
    __syncthreads();

    // reduce slots[256][8] -> 8 values
    {
        const int k = t & 7, r = t >> 3;  // r in 0..31
        float s = 0.f;
#pragma unroll
        for (int i = 0; i < 8; ++i) s += slots[(r + 32 * i) * 9 + k];
        red[r * 8 + k] = s;
    }
    __syncthreads();
    if (t < 8) {
        float s = 0.f;
#pragma unroll
        for (int r = 0; r < 32; ++r) s += red[r * 8 + t];
        atomicAdd(&sums[(b * NK + t) * NC + c], s);
    }
}

// ---------------------------------------------------------------------------
// Per-class pixel counts (labels only, 8 MB read -> trivial).
// grid = 256 blocks: b = blk>>5, 8192-pixel chunk each.
// ---------------------------------------------------------------------------
__global__ __launch_bounds__(256) void k_counts(const int* __restrict__ lab,
                                                float* __restrict__ counts) {
    __shared__ float slots[256 * 9];
    __shared__ float red[256];
    const int t = threadIdx.x;
    const int b = blockIdx.x >> 5;
    const int sub = blockIdx.x & 31;

    float* myslot = &slots[t * 9];
#pragma unroll
    for (int i = 0; i < 9; ++i) myslot[i] = 0.f;

    const int* lb = lab + (size_t)b * HW;
    const int base = sub * 8192;
    for (int it = 0; it < 8; ++it) {
        const int p = base + it * 1024 + t * 4;
        const int4 l4 = *reinterpret_cast<const int4*>(lb + p);
        myslot[l4.x] += 1.f;
        myslot[l4.y] += 1.f;
        myslot[l4.z] += 1.f;
        myslot[l4.w] += 1.f;
    }
    __syncthreads();
    {
        const int k = t & 7, r = t >> 3;
        float s = 0.f;
#pragma unroll
        for (int i = 0; i < 8; ++i) s += slots[(r + 32 * i) * 9 + k];
        red[r * 8 + k] = s;
    }
    __syncthreads();
    if (t < 8) {
        float s = 0.f;
#pragma unroll
        for (int r = 0; r < 32; ++r) s += red[r * 8 + t];
        atomicAdd(&counts[b * NK + t], s);
    }
}

// ---------------------------------------------------------------------------
// means (transposed [b][c][k]) from sums/counts. 2048 elements.
// ---------------------------------------------------------------------------
__global__ __launch_bounds__(256) void k_means(const float* __restrict__ sums,
                                               const float* __restrict__ counts,
                                               float* __restrict__ meansT) {
    const int idx = blockIdx.x * 256 + threadIdx.x;  // grid 8*256 = 2048
    const int b = idx >> 8;
    const int k = (idx >> 5) & 7;
    const int c = idx & 31;
    meansT[b * 256 + c * 8 + k] = sums[idx] / counts[b * NK + k];
}

// ---------------------------------------------------------------------------
// Pass 2: per-pixel distance to its class mean, segment-summed per class.
// One block = (image b, 1024-pixel chunk); 32-channel loop with means in LDS
// (transposed layout -> lanes hit 8 distinct banks, conflict-free).
// ---------------------------------------------------------------------------
__global__ __launch_bounds__(256) void k_dist(const float* __restrict__ emb,
                                              const int* __restrict__ lab,
                                              const float* __restrict__ meansT,
                                              float* __restrict__ distsum) {
    __shared__ float mT[256];
    __shared__ float slots[256 * 9];
    __shared__ float red[256];
    const int t = threadIdx.x;
    const int f = blockIdx.x;
    const int b = f & 7;
    const int chunk = f >> 3;  // 0..255

    mT[t] = meansT[b * 256 + t];
    float* myslot = &slots[t * 9];
#pragma unroll
    for (int i = 0; i < 9; ++i) myslot[i] = 0.f;
    __syncthreads();

    const int p = chunk * 1024 + t * 4;
    const int4 l4 = *reinterpret_cast<const int4*>(lab + (size_t)b * HW + p);
    const float* e = emb + (size_t)b * NC * HW + p;

    float a0 = 0.f, a1 = 0.f, a2 = 0.f, a3 = 0.f;
#pragma unroll 4
    for (int c = 0; c < NC; ++c) {
        const float4 e4 = *reinterpret_cast<const float4*>(e + (size_t)c * HW);
        const float* mrow = &mT[c * 8];
        float d0 = e4.x - mrow[l4.x];
        float d1 = e4.y - mrow[l4.y];
        float d2 = e4.z - mrow[l4.z];
        float d3 = e4.w - mrow[l4.w];
        a0 += d0 * d0;
        a1 += d1 * d1;
        a2 += d2 * d2;
        a3 += d3 * d3;
    }
    myslot[l4.x] += sqrtf(a0);
    myslot[l4.y] += sqrtf(a1);
    myslot[l4.z] += sqrtf(a2);
    myslot[l4.w] += sqrtf(a3);
    __syncthreads();

    {
        const int k = t & 7, r = t >> 3;
        float s = 0.f;
#pragma unroll
        for (int i = 0; i < 8; ++i) s += slots[(r + 32 * i) * 9 + k];
        red[r * 8 + k] = s;
    }
    __syncthreads();
    if (t < 8) {
        float s = 0.f;
#pragma unroll
        for (int r = 0; r < 32; ++r) s += red[r * 8 + t];
        atomicAdd(&distsum[b * NK + t], s);
    }
}

// ---------------------------------------------------------------------------
// Epilogue: var loss (sum over classes 1..7 of distsum/count) + pairwise
// hinge loss among means of clusters 1..7; average over images.
// Parallelized: 168 threads handle (image, pair); serial would cost ~25us.
// ---------------------------------------------------------------------------
__global__ __launch_bounds__(256) void k_final(const float* __restrict__ ws,
                                               float* __restrict__ out) {
    __shared__ float varl[8], distl[8], lossb[8];
    const int t = threadIdx.x;
    if (t < 8) { varl[t] = 0.f; distl[t] = 0.f; }
    __syncthreads();

    if (t < 64) {
        const int b = t >> 3, k = t & 7;
        if (k >= 1) {
            const float v = ws[WS_DS + b * NK + k] / ws[WS_CNT + b * NK + k];
            atomicAdd(&varl[b], v);
        }
    }
    if (t < 168) {  // 8 images * 21 pairs among clusters 1..7
        const int b = t / 21;
        const int pr = t - b * 21;
        int ii = 1, jj = 2, cnt = 0;
        for (int a = 1; a <= 7; ++a)
            for (int bb = a + 1; bb <= 7; ++bb) {
                if (cnt == pr) { ii = a; jj = bb; }
                ++cnt;
            }
        const float* mTb = ws + WS_MT + b * 256;
        float sq = 0.f;
#pragma unroll
        for (int c = 0; c < NC; ++c) {
            const float d = mTb[c * 8 + ii] - mTb[c * 8 + jj];
            sq += d * d;
        }
        const float dist = sqrtf(sq);
        const float gap = 5.0f - dist;  // 2*DD = 5.0
        const float h = (dist < 5.0f) ? gap * gap : 0.f;
        atomicAdd(&distl[b], h);
    }
    __syncthreads();
    if (t < 8) lossb[t] = (varl[t] + distl[t] * (1.0f / 6.0f)) * (1.0f / 7.0f);
    __syncthreads();
    if (t == 0) {
        float s = 0.f;
#pragma unroll
        for (int b = 0; b < 8; ++b) s += lossb[b];
        out[0] = s * 0.125f;
    }
}

extern "C" void kernel_launch(void* const* d_in, const int* in_sizes, int n_in,
                              void* d_out, int out_size, void* d_ws, size_t ws_size,
                              hipStream_t stream) {
    const float* emb = (const float*)d_in[0];
    const int* lab = (const int*)d_in[1];
    float* out = (float*)d_out;
    float* ws = (float*)d_ws;

    // Harness poisons d_ws once (0xAA) and never re-poisons: zero accumulators
    // every launch (graph-capturable).
    hipMemsetAsync(d_ws, 0, WS_FLOATS * sizeof(float), stream);

    k_sums<<<NB * 16 * NC, 256, 0, stream>>>(emb, lab, ws + WS_SUMS);
    k_counts<<<NB * 32, 256, 0, stream>>>(lab, ws + WS_CNT);
    k_means<<<8, 256, 0, stream>>>(ws + WS_SUMS, ws + WS_CNT, ws + WS_MT);
    k_dist<<<NB * 256, 256, 0, stream>>>(emb, lab, ws + WS_MT, ws + WS_DS);
    k_final<<<1, 256, 0, stream>>>(ws, out);
}